// Round 1
// baseline (138.609 us; speedup 1.0000x reference)
//
#include <hip/hip_runtime.h>
#include <math.h>

typedef float f32x4 __attribute__((ext_vector_type(4)));
typedef short s16x8 __attribute__((ext_vector_type(8)));

#define NROWS 8192
#define NCOLS 512
#define BHALF 4096
#define NT    64       // 8192 / 128 tiles per dim
#define BM    128
#define BK    64

// ---------- helpers ----------
__device__ __forceinline__ unsigned short f2bf(float f) {
    // RNE float -> bf16 (inputs are finite normals; no NaN handling needed)
    unsigned u = __builtin_bit_cast(unsigned, f);
    u += 0x7FFFu + ((u >> 16) & 1u);
    return (unsigned short)(u >> 16);
}

// ---------- tiny kernels ----------
__global__ void k_init(float* __restrict__ colsum, double* __restrict__ sacc) {
    int t = threadIdx.x;
    if (t < NCOLS) colsum[t] = 0.0f;
    if (t == 0) *sacc = 0.0;
}

// one row per wave; 2048 blocks x 256 threads
__global__ void k_sq(const float* __restrict__ src, const float* __restrict__ tgt,
                     float* __restrict__ sq) {
    int t = threadIdx.x;
    int row = blockIdx.x * 4 + (t >> 6);
    int l = t & 63;
    const float* base = (row < BHALF) ? (src + (size_t)row * NCOLS)
                                      : (tgt + (size_t)(row - BHALF) * NCOLS);
    const float4* p = (const float4*)base;
    float4 a = p[l * 2 + 0];
    float4 b = p[l * 2 + 1];
    float s = a.x*a.x + a.y*a.y + a.z*a.z + a.w*a.w
            + b.x*b.x + b.y*b.y + b.z*b.z + b.w*b.w;
    #pragma unroll
    for (int o = 32; o > 0; o >>= 1) s += __shfl_down(s, o);
    if (l == 0) sq[row] = s;
}

// column sums of concat(src,tgt): 128 blocks x 256 threads, 64 rows/block
__global__ void k_colsum(const float* __restrict__ src, const float* __restrict__ tgt,
                         float* __restrict__ colsum) {
    int b = blockIdx.x;
    int t = threadIdx.x;
    int r0 = b * 64;
    const float* base0 = (r0 < BHALF) ? (src + (size_t)r0 * NCOLS)
                                      : (tgt + (size_t)(r0 - BHALF) * NCOLS);
    float a0 = 0.f, a1 = 0.f;
    for (int r = 0; r < 64; ++r) {
        const float* row = base0 + (size_t)r * NCOLS;
        a0 += row[t];
        a1 += row[t + 256];
    }
    atomicAdd(&colsum[t], a0);
    atomicAdd(&colsum[t + 256], a1);
}

// bandwidth from analytic sum(l2) = 2n*T - 2*||colsum||^2 ; store log2(e)/bw_k
__global__ void k_bw(const float* __restrict__ sq, const float* __restrict__ colsum,
                     float* __restrict__ cvals) {
    __shared__ double red[512];
    __shared__ double sT;
    int t = threadIdx.x;
    double acc = 0.0;
    for (int i = t; i < NROWS; i += 512) acc += (double)sq[i];
    red[t] = acc; __syncthreads();
    for (int o = 256; o > 0; o >>= 1) { if (t < o) red[t] += red[t + o]; __syncthreads(); }
    if (t == 0) sT = red[0];
    __syncthreads();
    double c = (double)colsum[t];
    red[t] = c * c; __syncthreads();
    for (int o = 256; o > 0; o >>= 1) { if (t < o) red[t] += red[t + o]; __syncthreads(); }
    if (t == 0) {
        double G = red[0];
        double sum_l2 = 2.0 * (double)NROWS * sT - 2.0 * G;
        double denom = (double)NROWS * (double)NROWS - (double)NROWS;
        double bw = sum_l2 / denom / 4.0;   // KERNEL_MUL^(KERNEL_NUM/2) = 4
        const double L2E = 1.4426950408889634;
        double b = bw;
        #pragma unroll
        for (int k = 0; k < 5; ++k) { cvals[k] = (float)(L2E / b); b *= 2.0; }
    }
}

// ---------- main fused MMD kernel ----------
// 128x128 tile per block, 4 waves (2x2), wave tile 64x64 via 4x4 of 16x16x32 MFMA.
// Upper-triangle tiles only (tj >= ti), weight 2 off-diag, {2,1,0} within diagonal tiles.
__global__ __launch_bounds__(256, 2)
void k_mmd(const float* __restrict__ src, const float* __restrict__ tgt,
           const float* __restrict__ sq, const float* __restrict__ cvals,
           double* __restrict__ sacc) {
    __shared__ short As[BM * BK];
    __shared__ short Bs[BM * BK];
    __shared__ float wred[4];

    // triangular block mapping: row ti has (NT - ti) blocks
    int rem = blockIdx.x;
    int ti = 0;
    while (rem >= NT - ti) { rem -= NT - ti; ++ti; }
    int tj = ti + rem;

    const int t  = threadIdx.x;
    const int w  = t >> 6;       // wave 0..3
    const int l  = t & 63;
    const int wr = w >> 1, wc = w & 1;
    const int lr = l & 15;       // fragment row/col lane
    const int lk = l >> 4;       // 0..3 k-group

    const int rowA0 = ti * BM, rowB0 = tj * BM;
    const float* baseA = (rowA0 < BHALF) ? (src + (size_t)rowA0 * NCOLS)
                                         : (tgt + (size_t)(rowA0 - BHALF) * NCOLS);
    const float* baseB = (rowB0 < BHALF) ? (src + (size_t)rowB0 * NCOLS)
                                         : (tgt + (size_t)(rowB0 - BHALF) * NCOLS);

    f32x4 acc[4][4] = {};

    for (int kt = 0; kt < NCOLS / BK; ++kt) {
        __syncthreads();   // previous compute done before overwriting LDS
        // stage A and B tiles: 1024 16B-chunks each, 256 threads x 4 iters.
        // LDS chunk (row, slot) holds global chunk (row, slot ^ (row&7)).
        #pragma unroll
        for (int i = 0; i < 4; ++i) {
            int qq   = i * 256 + t;
            int row  = qq >> 3;
            int slot = qq & 7;
            int ss   = slot ^ (row & 7);
            {
                const float* gp = baseA + (size_t)row * NCOLS + kt * BK + ss * 8;
                float4 f0 = ((const float4*)gp)[0];
                float4 f1 = ((const float4*)gp)[1];
                s16x8 v;
                v[0] = (short)f2bf(f0.x); v[1] = (short)f2bf(f0.y);
                v[2] = (short)f2bf(f0.z); v[3] = (short)f2bf(f0.w);
                v[4] = (short)f2bf(f1.x); v[5] = (short)f2bf(f1.y);
                v[6] = (short)f2bf(f1.z); v[7] = (short)f2bf(f1.w);
                ((s16x8*)As)[qq] = v;
            }
            {
                const float* gp = baseB + (size_t)row * NCOLS + kt * BK + ss * 8;
                float4 f0 = ((const float4*)gp)[0];
                float4 f1 = ((const float4*)gp)[1];
                s16x8 v;
                v[0] = (short)f2bf(f0.x); v[1] = (short)f2bf(f0.y);
                v[2] = (short)f2bf(f0.z); v[3] = (short)f2bf(f0.w);
                v[4] = (short)f2bf(f1.x); v[5] = (short)f2bf(f1.y);
                v[6] = (short)f2bf(f1.z); v[7] = (short)f2bf(f1.w);
                ((s16x8*)Bs)[qq] = v;
            }
        }
        __syncthreads();
        // compute: two 32-deep k-steps per LDS tile
        #pragma unroll
        for (int kk = 0; kk < 2; ++kk) {
            s16x8 af[4], bf[4];
            int slotd = kk * 4 + lk;
            #pragma unroll
            for (int m = 0; m < 4; ++m) {
                int row = wr * 64 + m * 16 + lr;
                int sl  = slotd ^ (row & 7);
                af[m] = ((const s16x8*)As)[row * 8 + sl];
            }
            #pragma unroll
            for (int n = 0; n < 4; ++n) {
                int row = wc * 64 + n * 16 + lr;
                int sl  = slotd ^ (row & 7);
                bf[n] = ((const s16x8*)Bs)[row * 8 + sl];
            }
            #pragma unroll
            for (int m = 0; m < 4; ++m)
                #pragma unroll
                for (int n = 0; n < 4; ++n)
                    acc[m][n] = __builtin_amdgcn_mfma_f32_16x16x32_bf16(
                        af[m], bf[n], acc[m][n], 0, 0, 0);
        }
    }

    // ---------- epilogue: l2 -> 5 exps -> signed/weighted sum ----------
    float c0 = cvals[0], c1 = cvals[1], c2 = cvals[2], c3 = cvals[3], c4 = cvals[4];
    float sqa[4][4], sqb[4];
    #pragma unroll
    for (int m = 0; m < 4; ++m)
        #pragma unroll
        for (int r = 0; r < 4; ++r)
            sqa[m][r] = sq[rowA0 + wr * 64 + m * 16 + lk * 4 + r];
    #pragma unroll
    for (int n = 0; n < 4; ++n)
        sqb[n] = sq[rowB0 + wc * 64 + n * 16 + lr];

    const bool diag = (ti == tj);
    const float sgn = ((rowA0 < BHALF) == (rowB0 < BHALF)) ? 1.f : -1.f;
    float local = 0.f;
    #pragma unroll
    for (int m = 0; m < 4; ++m)
        #pragma unroll
        for (int n = 0; n < 4; ++n)
            #pragma unroll
            for (int r = 0; r < 4; ++r) {
                float d  = acc[m][n][r];
                float l2 = sqa[m][r] + sqb[n] - 2.f * d;
                float e  = exp2f(-l2 * c0) + exp2f(-l2 * c1) + exp2f(-l2 * c2)
                         + exp2f(-l2 * c3) + exp2f(-l2 * c4);
                if (diag) {
                    int gi = rowA0 + wr * 64 + m * 16 + lk * 4 + r;
                    int gj = rowB0 + wc * 64 + n * 16 + lr;
                    float wgt = (gj > gi) ? 2.f : ((gj == gi) ? 1.f : 0.f);
                    local += wgt * e;
                } else {
                    local += e;
                }
            }
    if (!diag) local *= 2.f * sgn;   // diagonal tiles always sgn=+1

    #pragma unroll
    for (int o = 32; o > 0; o >>= 1) local += __shfl_down(local, o);
    if (l == 0) wred[w] = local;
    __syncthreads();
    if (t == 0) {
        float bsum = wred[0] + wred[1] + wred[2] + wred[3];
        atomicAdd(sacc, (double)bsum);
    }
}

__global__ void k_final(const double* __restrict__ sacc, float* __restrict__ out) {
    out[0] = (float)(*sacc * (1.0 / ((double)BHALF * (double)BHALF)));
}

// ---------- launch ----------
extern "C" void kernel_launch(void* const* d_in, const int* in_sizes, int n_in,
                              void* d_out, int out_size, void* d_ws, size_t ws_size,
                              hipStream_t stream) {
    (void)in_sizes; (void)n_in; (void)out_size; (void)ws_size;
    const float* src = (const float*)d_in[0];
    const float* tgt = (const float*)d_in[1];
    float* out = (float*)d_out;
    char* ws = (char*)d_ws;
    float*  sq     = (float*) (ws);            // 8192 * 4 = 32768 B
    float*  colsum = (float*) (ws + 32768);    // 512 * 4  = 2048 B
    double* sacc   = (double*)(ws + 34816);    // 8 B (8-aligned)
    float*  cvals  = (float*) (ws + 34824);    // 5 * 4 B

    k_init  <<<1, 512, 0, stream>>>(colsum, sacc);
    k_sq    <<<NROWS / 4, 256, 0, stream>>>(src, tgt, sq);
    k_colsum<<<128, 256, 0, stream>>>(src, tgt, colsum);
    k_bw    <<<1, 512, 0, stream>>>(sq, colsum, cvals);
    k_mmd   <<<NT * (NT + 1) / 2, 256, 0, stream>>>(src, tgt, sq, cvals, sacc);
    k_final <<<1, 1, 0, stream>>>(sacc, out);
}

// Round 3
// 109.337 us; speedup vs baseline: 1.2677x; 1.2677x over previous
//
#include <hip/hip_runtime.h>
#include <math.h>

typedef float f32x4 __attribute__((ext_vector_type(4)));
typedef short s16x8 __attribute__((ext_vector_type(8)));

#define NROWS 8192
#define NCOLS 512
#define BHALF 4096
#define NT    64       // 8192 / 128 tiles per dim
#define BM    128
#define BK    64
#define NBLK  (NT * (NT + 1) / 2)   // 2080 triangular tiles
#define CSPART 256                   // colsum partial blocks

typedef __attribute__((address_space(1))) const unsigned int guint;
typedef __attribute__((address_space(3))) unsigned int luint;

// ---------- helpers ----------
__device__ __forceinline__ unsigned short f2bf(float f) {
    // RNE float -> bf16 (inputs are finite normals; no NaN handling needed)
    unsigned u = __builtin_bit_cast(unsigned, f);
    u += 0x7FFFu + ((u >> 16) & 1u);
    return (unsigned short)(u >> 16);
}

// ---------- conversion + row-sq (fused) ----------
// one row per wave; 2048 blocks x 256 threads
__global__ void k_conv(const float* __restrict__ src, const float* __restrict__ tgt,
                       short* __restrict__ bfall, float* __restrict__ sq) {
    int t = threadIdx.x;
    int row = blockIdx.x * 4 + (t >> 6);
    int l = t & 63;
    const float* base = (row < BHALF) ? (src + (size_t)row * NCOLS)
                                      : (tgt + (size_t)(row - BHALF) * NCOLS);
    const float4* p = (const float4*)base;
    float4 a = p[l * 2 + 0];
    float4 b = p[l * 2 + 1];
    s16x8 v;
    v[0] = (short)f2bf(a.x); v[1] = (short)f2bf(a.y);
    v[2] = (short)f2bf(a.z); v[3] = (short)f2bf(a.w);
    v[4] = (short)f2bf(b.x); v[5] = (short)f2bf(b.y);
    v[6] = (short)f2bf(b.z); v[7] = (short)f2bf(b.w);
    ((s16x8*)(bfall + (size_t)row * NCOLS))[l] = v;
    float s = a.x*a.x + a.y*a.y + a.z*a.z + a.w*a.w
            + b.x*b.x + b.y*b.y + b.z*b.z + b.w*b.w;
    #pragma unroll
    for (int o = 32; o > 0; o >>= 1) s += __shfl_down(s, o);
    if (l == 0) sq[row] = s;
}

// column-sum partials (deterministic, no atomics): CSPART blocks x 256 threads,
// 32 rows/block; block b writes colsum_part[b][0..511]
__global__ void k_colsum(const float* __restrict__ src, const float* __restrict__ tgt,
                         float* __restrict__ colsum_part) {
    int b = blockIdx.x;
    int t = threadIdx.x;
    int r0 = b * 32;
    const float* base0 = (r0 < BHALF) ? (src + (size_t)r0 * NCOLS)
                                      : (tgt + (size_t)(r0 - BHALF) * NCOLS);
    float a0 = 0.f, a1 = 0.f;
    for (int r = 0; r < 32; ++r) {
        const float* row = base0 + (size_t)r * NCOLS;
        a0 += row[t];
        a1 += row[t + 256];
    }
    colsum_part[(size_t)b * NCOLS + t]       = a0;
    colsum_part[(size_t)b * NCOLS + t + 256] = a1;
}

// bandwidth from analytic sum(l2) = 2n*T - 2*||colsum||^2 ; store log2(e)/bw_k
// fully fixed-order -> deterministic
__global__ void k_bw(const float* __restrict__ sq, const float* __restrict__ colsum_part,
                     float* __restrict__ cvals) {
    __shared__ double red[512];
    __shared__ double sT;
    int t = threadIdx.x;
    double acc = 0.0;
    for (int i = t; i < NROWS; i += 512) acc += (double)sq[i];
    red[t] = acc; __syncthreads();
    for (int o = 256; o > 0; o >>= 1) { if (t < o) red[t] += red[t + o]; __syncthreads(); }
    if (t == 0) sT = red[0];
    __syncthreads();
    double c = 0.0;
    for (int p = 0; p < CSPART; ++p) c += (double)colsum_part[(size_t)p * NCOLS + t];
    red[t] = c * c; __syncthreads();
    for (int o = 256; o > 0; o >>= 1) { if (t < o) red[t] += red[t + o]; __syncthreads(); }
    if (t == 0) {
        double G = red[0];
        double sum_l2 = 2.0 * (double)NROWS * sT - 2.0 * G;
        double denom = (double)NROWS * (double)NROWS - (double)NROWS;
        double bw = sum_l2 / denom / 4.0;   // KERNEL_MUL^(KERNEL_NUM/2) = 4
        const double L2E = 1.4426950408889634;
        double b = bw;
        #pragma unroll
        for (int k = 0; k < 5; ++k) { cvals[k] = (float)(L2E / b); b *= 2.0; }
    }
}

// ---------- main fused MMD kernel ----------
// 128x128 tile per block, 4 waves (2x2), wave tile 64x64 via 4x4 of 16x16x32 MFMA.
// Staging via global_load_lds (linear LDS dest, pre-swizzled global source).
// Upper-triangle tiles only (tj >= ti), weight 2 off-diag, {2,1,0} within diagonal tiles.
// Block partial written to psum[blockIdx.x] (no atomics -> deterministic).
__global__ __launch_bounds__(256, 4)
void k_mmd(const short* __restrict__ bfall, const float* __restrict__ sq,
           const float* __restrict__ cvals, double* __restrict__ psum) {
    __shared__ short As[BM * BK];
    __shared__ short Bs[BM * BK];
    __shared__ float wred[4];

    // triangular block mapping: row ti has (NT - ti) blocks
    int rem = blockIdx.x;
    int ti = 0;
    while (rem >= NT - ti) { rem -= NT - ti; ++ti; }
    int tj = ti + rem;

    const int t  = threadIdx.x;
    const int w  = t >> 6;       // wave 0..3
    const int l  = t & 63;
    const int wr = w >> 1, wc = w & 1;
    const int lr = l & 15;       // fragment row/col lane
    const int lk = l >> 4;       // 0..3 k-group

    const int rowA0 = ti * BM, rowB0 = tj * BM;
    const short* gA = bfall + (size_t)rowA0 * NCOLS;
    const short* gB = bfall + (size_t)rowB0 * NCOLS;

    f32x4 acc[4][4] = {};

    for (int kt = 0; kt < NCOLS / BK; ++kt) {
        __syncthreads();   // previous compute done before overwriting LDS
        #pragma unroll
        for (int i = 0; i < 4; ++i) {
            int q    = (w * 4 + i) * 64 + l;   // 16B-chunk index 0..1023
            int row  = q >> 3;
            int slot = q & 7;
            int ss   = slot ^ (row & 7);
            const short* ga = gA + (size_t)row * NCOLS + kt * BK + ss * 8;
            const short* gb = gB + (size_t)row * NCOLS + kt * BK + ss * 8;
            short* la = As + (size_t)(w * 4 + i) * 64 * 8;  // wave-uniform base
            short* lb = Bs + (size_t)(w * 4 + i) * 64 * 8;
            __builtin_amdgcn_global_load_lds((guint*)ga, (luint*)la, 16, 0, 0);
            __builtin_amdgcn_global_load_lds((guint*)gb, (luint*)lb, 16, 0, 0);
        }
        __syncthreads();   // drains vmcnt: tiles ready
        // compute: two 32-deep k-steps per LDS tile
        #pragma unroll
        for (int kk = 0; kk < 2; ++kk) {
            s16x8 af[4], bf[4];
            int slotd = kk * 4 + lk;
            #pragma unroll
            for (int m = 0; m < 4; ++m) {
                int row = wr * 64 + m * 16 + lr;
                int sl  = slotd ^ (row & 7);
                af[m] = ((const s16x8*)As)[row * 8 + sl];
            }
            #pragma unroll
            for (int n = 0; n < 4; ++n) {
                int row = wc * 64 + n * 16 + lr;
                int sl  = slotd ^ (row & 7);
                bf[n] = ((const s16x8*)Bs)[row * 8 + sl];
            }
            #pragma unroll
            for (int m = 0; m < 4; ++m)
                #pragma unroll
                for (int n = 0; n < 4; ++n)
                    acc[m][n] = __builtin_amdgcn_mfma_f32_16x16x32_bf16(
                        af[m], bf[n], acc[m][n], 0, 0, 0);
        }
    }

    // ---------- epilogue: l2 -> 5 exps -> signed/weighted sum ----------
    float c0 = cvals[0], c1 = cvals[1], c2 = cvals[2], c3 = cvals[3], c4 = cvals[4];
    float sqa[4][4], sqb[4];
    #pragma unroll
    for (int m = 0; m < 4; ++m)
        #pragma unroll
        for (int r = 0; r < 4; ++r)
            sqa[m][r] = sq[rowA0 + wr * 64 + m * 16 + lk * 4 + r];
    #pragma unroll
    for (int n = 0; n < 4; ++n)
        sqb[n] = sq[rowB0 + wc * 64 + n * 16 + lr];

    const bool diag = (ti == tj);
    const float sgn = ((rowA0 < BHALF) == (rowB0 < BHALF)) ? 1.f : -1.f;
    float local = 0.f;
    #pragma unroll
    for (int m = 0; m < 4; ++m)
        #pragma unroll
        for (int n = 0; n < 4; ++n)
            #pragma unroll
            for (int r = 0; r < 4; ++r) {
                float d  = acc[m][n][r];
                float l2 = sqa[m][r] + sqb[n] - 2.f * d;
                float e  = exp2f(-l2 * c0) + exp2f(-l2 * c1) + exp2f(-l2 * c2)
                         + exp2f(-l2 * c3) + exp2f(-l2 * c4);
                if (diag) {
                    int gi = rowA0 + wr * 64 + m * 16 + lk * 4 + r;
                    int gj = rowB0 + wc * 64 + n * 16 + lr;
                    float wgt = (gj > gi) ? 2.f : ((gj == gi) ? 1.f : 0.f);
                    local += wgt * e;
                } else {
                    local += e;
                }
            }
    if (!diag) local *= 2.f * sgn;   // diagonal tiles always sgn=+1

    #pragma unroll
    for (int o = 32; o > 0; o >>= 1) local += __shfl_down(local, o);
    if (l == 0) wred[w] = local;
    __syncthreads();
    if (t == 0) {
        psum[blockIdx.x] = (double)(wred[0] + wred[1] + wred[2] + wred[3]);
    }
}

// fixed-order final reduction over NBLK partials -> loss
__global__ void k_final(const double* __restrict__ psum, float* __restrict__ out) {
    __shared__ double red[256];
    int t = threadIdx.x;
    double a = 0.0;
    for (int i = t; i < NBLK; i += 256) a += psum[i];
    red[t] = a; __syncthreads();
    for (int o = 128; o > 0; o >>= 1) { if (t < o) red[t] += red[t + o]; __syncthreads(); }
    if (t == 0) out[0] = (float)(red[0] * (1.0 / ((double)BHALF * (double)BHALF)));
}

// ---------- launch ----------
extern "C" void kernel_launch(void* const* d_in, const int* in_sizes, int n_in,
                              void* d_out, int out_size, void* d_ws, size_t ws_size,
                              hipStream_t stream) {
    (void)in_sizes; (void)n_in; (void)out_size; (void)ws_size;
    const float* src = (const float*)d_in[0];
    const float* tgt = (const float*)d_in[1];
    float* out = (float*)d_out;
    char* ws = (char*)d_ws;
    // layout (all offsets 16B-aligned; every consumed word is rewritten each call):
    short*  bfall  = (short*) (ws);                      // 8192*512*2 = 8388608 B
    float*  sq     = (float*) (ws + 8388608);            // 8192*4 = 32768 B
    float*  cspart = (float*) (ws + 8388608 + 32768);    // 256*512*4 = 524288 B
    float*  cvals  = (float*) (ws + 8388608 + 32768 + 524288);        // 20 B
    double* psum   = (double*)(ws + 8388608 + 32768 + 524288 + 32);   // 2080*8 = 16640 B

    k_conv  <<<NROWS / 4, 256, 0, stream>>>(src, tgt, bfall, sq);
    k_colsum<<<CSPART, 256, 0, stream>>>(src, tgt, cspart);
    k_bw    <<<1, 512, 0, stream>>>(sq, cspart, cvals);
    k_mmd   <<<NBLK, 256, 0, stream>>>(bfall, sq, cvals, psum);
    k_final <<<1, 256, 0, stream>>>(psum, out);
}

// Round 4
// 97.771 us; speedup vs baseline: 1.4177x; 1.1183x over previous
//
#include <hip/hip_runtime.h>
#include <math.h>

typedef float f32x4 __attribute__((ext_vector_type(4)));
typedef short s16x8 __attribute__((ext_vector_type(8)));

#define NROWS 8192
#define NCOLS 512
#define BHALF 4096
#define NT    64       // 8192 / 128 tiles per dim
#define BM    128
#define BK    64
#define NKT   (NCOLS / BK)          // 8 K-steps
#define NBLK  (NT * (NT + 1) / 2)   // 2080 triangular tiles
#define CSPART 256                   // colsum partial blocks

typedef __attribute__((address_space(1))) const unsigned int guint;
typedef __attribute__((address_space(3))) unsigned int luint;

// ---------- helpers ----------
__device__ __forceinline__ unsigned short f2bf(float f) {
    // RNE float -> bf16 (inputs are finite normals; no NaN handling needed)
    unsigned u = __builtin_bit_cast(unsigned, f);
    u += 0x7FFFu + ((u >> 16) & 1u);
    return (unsigned short)(u >> 16);
}

// ---------- conversion + row-sq (fused) ----------
// one row per wave; 2048 blocks x 256 threads
__global__ void k_conv(const float* __restrict__ src, const float* __restrict__ tgt,
                       short* __restrict__ bfall, float* __restrict__ sq) {
    int t = threadIdx.x;
    int row = blockIdx.x * 4 + (t >> 6);
    int l = t & 63;
    const float* base = (row < BHALF) ? (src + (size_t)row * NCOLS)
                                      : (tgt + (size_t)(row - BHALF) * NCOLS);
    const float4* p = (const float4*)base;
    float4 a = p[l * 2 + 0];
    float4 b = p[l * 2 + 1];
    s16x8 v;
    v[0] = (short)f2bf(a.x); v[1] = (short)f2bf(a.y);
    v[2] = (short)f2bf(a.z); v[3] = (short)f2bf(a.w);
    v[4] = (short)f2bf(b.x); v[5] = (short)f2bf(b.y);
    v[6] = (short)f2bf(b.z); v[7] = (short)f2bf(b.w);
    ((s16x8*)(bfall + (size_t)row * NCOLS))[l] = v;
    float s = a.x*a.x + a.y*a.y + a.z*a.z + a.w*a.w
            + b.x*b.x + b.y*b.y + b.z*b.z + b.w*b.w;
    #pragma unroll
    for (int o = 32; o > 0; o >>= 1) s += __shfl_down(s, o);
    if (l == 0) sq[row] = s;
}

// column-sum partials (deterministic, no atomics): CSPART blocks x 256 threads,
// 32 rows/block; block b writes colsum_part[b][0..511]
__global__ void k_colsum(const float* __restrict__ src, const float* __restrict__ tgt,
                         float* __restrict__ colsum_part) {
    int b = blockIdx.x;
    int t = threadIdx.x;
    int r0 = b * 32;
    const float* base0 = (r0 < BHALF) ? (src + (size_t)r0 * NCOLS)
                                      : (tgt + (size_t)(r0 - BHALF) * NCOLS);
    float a0 = 0.f, a1 = 0.f;
    for (int r = 0; r < 32; ++r) {
        const float* row = base0 + (size_t)r * NCOLS;
        a0 += row[t];
        a1 += row[t + 256];
    }
    colsum_part[(size_t)b * NCOLS + t]       = a0;
    colsum_part[(size_t)b * NCOLS + t + 256] = a1;
}

// bandwidth from analytic sum(l2) = 2n*T - 2*||colsum||^2 ; store log2(e)/bw_k
// fully fixed-order -> deterministic
__global__ void k_bw(const float* __restrict__ sq, const float* __restrict__ colsum_part,
                     float* __restrict__ cvals) {
    __shared__ double red[512];
    __shared__ double sT;
    int t = threadIdx.x;
    double acc = 0.0;
    for (int i = t; i < NROWS; i += 512) acc += (double)sq[i];
    red[t] = acc; __syncthreads();
    for (int o = 256; o > 0; o >>= 1) { if (t < o) red[t] += red[t + o]; __syncthreads(); }
    if (t == 0) sT = red[0];
    __syncthreads();
    double c = 0.0;
    for (int p = 0; p < CSPART; ++p) c += (double)colsum_part[(size_t)p * NCOLS + t];
    red[t] = c * c; __syncthreads();
    for (int o = 256; o > 0; o >>= 1) { if (t < o) red[t] += red[t + o]; __syncthreads(); }
    if (t == 0) {
        double G = red[0];
        double sum_l2 = 2.0 * (double)NROWS * sT - 2.0 * G;
        double denom = (double)NROWS * (double)NROWS - (double)NROWS;
        double bw = sum_l2 / denom / 4.0;   // KERNEL_MUL^(KERNEL_NUM/2) = 4
        const double L2E = 1.4426950408889634;
        double b = bw;
        #pragma unroll
        for (int k = 0; k < 5; ++k) { cvals[k] = (float)(L2E / b); b *= 2.0; }
    }
}

// ---------- main fused MMD kernel ----------
// 128x128 tile per block, 4 waves (2x2), wave tile 64x64 via 4x4 of 16x16x32 MFMA.
// Double-buffered LDS; stage(kt+1) issued before compute(kt); one barrier/iter.
// Staging via global_load_lds (linear LDS dest, pre-swizzled global source).
// Kernel sum via exp square-chain: x=2^(-l2*c4); sum = x+x^2+x^4+x^8+x^16.
// Upper-triangle tiles only (tj >= ti); block partial -> psum (deterministic).
__global__ __launch_bounds__(256, 2)
void k_mmd(const short* __restrict__ bfall, const float* __restrict__ sq,
           const float* __restrict__ cvals, double* __restrict__ psum) {
    __shared__ short As[2][BM * BK];
    __shared__ short Bs[2][BM * BK];
    __shared__ float wred[4];

    // triangular block mapping: row ti has (NT - ti) blocks
    int rem = blockIdx.x;
    int ti = 0;
    while (rem >= NT - ti) { rem -= NT - ti; ++ti; }
    int tj = ti + rem;

    const int t  = threadIdx.x;
    const int w  = t >> 6;       // wave 0..3
    const int l  = t & 63;
    const int wr = w >> 1, wc = w & 1;
    const int lr = l & 15;       // fragment row/col lane
    const int lk = l >> 4;       // 0..3 k-group

    const int rowA0 = ti * BM, rowB0 = tj * BM;
    const short* gA = bfall + (size_t)rowA0 * NCOLS;
    const short* gB = bfall + (size_t)rowB0 * NCOLS;

    // per-wave staging geometry (kt-invariant): 4 chunks of 64 lanes
    int q0   = (w * 4) * 64 + l;           // base chunk id for i=0
    // stage macro: issues 8 global_load_lds for tile kt into buffer bsel
    #define STAGE(bsel, kt)                                                        \
        _Pragma("unroll")                                                          \
        for (int i = 0; i < 4; ++i) {                                              \
            int q    = q0 + i * 64;                                                \
            int row  = q >> 3;                                                     \
            int slot = q & 7;                                                      \
            int ss   = slot ^ (row & 7);                                           \
            const short* ga = gA + (size_t)row * NCOLS + (kt) * BK + ss * 8;       \
            const short* gb = gB + (size_t)row * NCOLS + (kt) * BK + ss * 8;       \
            short* la = &As[bsel][(size_t)q * 8];                                  \
            short* lb = &Bs[bsel][(size_t)q * 8];                                  \
            __builtin_amdgcn_global_load_lds((guint*)ga, (luint*)la, 16, 0, 0);    \
            __builtin_amdgcn_global_load_lds((guint*)gb, (luint*)lb, 16, 0, 0);    \
        }

    f32x4 acc[4][4] = {};

    // prologue: stage tile 0 into buffer 0; hoist sq[] epilogue operands
    STAGE(0, 0);
    float sqa[4][4], sqb[4];
    #pragma unroll
    for (int m = 0; m < 4; ++m)
        #pragma unroll
        for (int r = 0; r < 4; ++r)
            sqa[m][r] = sq[rowA0 + wr * 64 + m * 16 + lk * 4 + r];
    #pragma unroll
    for (int n = 0; n < 4; ++n)
        sqb[n] = sq[rowB0 + wc * 64 + n * 16 + lr];
    float c4 = cvals[4];
    __syncthreads();   // drains vmcnt: tile 0 ready

    int cur = 0;
    for (int kt = 0; kt < NKT; ++kt) {
        if (kt + 1 < NKT) { STAGE(cur ^ 1, kt + 1); }   // prefetch next tile
        // compute current tile: two 32-deep k-steps
        #pragma unroll
        for (int kk = 0; kk < 2; ++kk) {
            s16x8 af[4], bf[4];
            int slotd = kk * 4 + lk;
            #pragma unroll
            for (int m = 0; m < 4; ++m) {
                int row = wr * 64 + m * 16 + lr;
                int sl  = slotd ^ (row & 7);
                af[m] = ((const s16x8*)As[cur])[row * 8 + sl];
            }
            #pragma unroll
            for (int n = 0; n < 4; ++n) {
                int row = wc * 64 + n * 16 + lr;
                int sl  = slotd ^ (row & 7);
                bf[n] = ((const s16x8*)Bs[cur])[row * 8 + sl];
            }
            #pragma unroll
            for (int m = 0; m < 4; ++m)
                #pragma unroll
                for (int n = 0; n < 4; ++n)
                    acc[m][n] = __builtin_amdgcn_mfma_f32_16x16x32_bf16(
                        af[m], bf[n], acc[m][n], 0, 0, 0);
        }
        __syncthreads();   // all reads of 'cur' done; vmcnt drained -> next ready
        cur ^= 1;
    }
    #undef STAGE

    // ---------- epilogue: l2 -> exp square-chain -> signed/weighted sum ----------
    const bool diag = (ti == tj);
    const float sgn = ((rowA0 < BHALF) == (rowB0 < BHALF)) ? 1.f : -1.f;
    float local = 0.f;
    #pragma unroll
    for (int m = 0; m < 4; ++m)
        #pragma unroll
        for (int n = 0; n < 4; ++n)
            #pragma unroll
            for (int r = 0; r < 4; ++r) {
                float d  = acc[m][n][r];
                float l2 = sqa[m][r] + sqb[n] - 2.f * d;
                // e_k = exp(-l2/(bw*2^k)) = x^(2^(4-k)), x = 2^(-l2*c4)
                float x  = exp2f(-l2 * c4);
                float x2 = x * x;
                float x4 = x2 * x2;
                float x8 = x4 * x4;
                float e  = x + x2 + x4 + x8 + x8 * x8;
                if (diag) {
                    int gi = rowA0 + wr * 64 + m * 16 + lk * 4 + r;
                    int gj = rowB0 + wc * 64 + n * 16 + lr;
                    float wgt = (gj > gi) ? 2.f : ((gj == gi) ? 1.f : 0.f);
                    local += wgt * e;
                } else {
                    local += e;
                }
            }
    if (!diag) local *= 2.f * sgn;   // diagonal tiles always sgn=+1

    #pragma unroll
    for (int o = 32; o > 0; o >>= 1) local += __shfl_down(local, o);
    if (l == 0) wred[w] = local;
    __syncthreads();
    if (t == 0) {
        psum[blockIdx.x] = (double)(wred[0] + wred[1] + wred[2] + wred[3]);
    }
}

// fixed-order final reduction over NBLK partials -> loss
__global__ void k_final(const double* __restrict__ psum, float* __restrict__ out) {
    __shared__ double red[256];
    int t = threadIdx.x;
    double a = 0.0;
    for (int i = t; i < NBLK; i += 256) a += psum[i];
    red[t] = a; __syncthreads();
    for (int o = 128; o > 0; o >>= 1) { if (t < o) red[t] += red[t + o]; __syncthreads(); }
    if (t == 0) out[0] = (float)(red[0] * (1.0 / ((double)BHALF * (double)BHALF)));
}

// ---------- launch ----------
extern "C" void kernel_launch(void* const* d_in, const int* in_sizes, int n_in,
                              void* d_out, int out_size, void* d_ws, size_t ws_size,
                              hipStream_t stream) {
    (void)in_sizes; (void)n_in; (void)out_size; (void)ws_size;
    const float* src = (const float*)d_in[0];
    const float* tgt = (const float*)d_in[1];
    float* out = (float*)d_out;
    char* ws = (char*)d_ws;
    // layout (all offsets 16B-aligned; every consumed word is rewritten each call):
    short*  bfall  = (short*) (ws);                      // 8192*512*2 = 8388608 B
    float*  sq     = (float*) (ws + 8388608);            // 8192*4 = 32768 B
    float*  cspart = (float*) (ws + 8388608 + 32768);    // 256*512*4 = 524288 B
    float*  cvals  = (float*) (ws + 8388608 + 32768 + 524288);        // 20 B
    double* psum   = (double*)(ws + 8388608 + 32768 + 524288 + 32);   // 2080*8 = 16640 B

    k_conv  <<<NROWS / 4, 256, 0, stream>>>(src, tgt, bfall, sq);
    k_colsum<<<CSPART, 256, 0, stream>>>(src, tgt, cspart);
    k_bw    <<<1, 512, 0, stream>>>(sq, cspart, cvals);
    k_mmd   <<<NBLK, 256, 0, stream>>>(bfall, sq, cvals, psum);
    k_final <<<1, 256, 0, stream>>>(psum, out);
}